// Round 10
// baseline (2136.770 us; speedup 1.0000x reference)
//
#include <hip/hip_runtime.h>

typedef unsigned short u16;
typedef unsigned int   u32;

typedef __attribute__((ext_vector_type(8))) short bf16x8;
typedef __attribute__((ext_vector_type(4))) float f32x4;

// ---------- helpers ----------
__device__ __forceinline__ u16 f2bf(float v) {           // RNE fp32 -> bf16
    u32 u = __float_as_uint(v);
    u32 r = (u + 0x7fffu + ((u >> 16) & 1u)) >> 16;
    return (u16)r;
}
__device__ __forceinline__ float bf2f(u16 h) { return __uint_as_float(((u32)h) << 16); }

__device__ __forceinline__ float ftanh(float x) {        // tanh via exp, ~5 inst
    float e = __expf(2.0f * x);                          // inf for large x -> rcp gives 0 -> +1
    return 1.0f - 2.0f * __builtin_amdgcn_rcpf(e + 1.0f);
}

__device__ __forceinline__ void gl2lds16(const void* g, void* l) {
    __builtin_amdgcn_global_load_lds(
        (const __attribute__((address_space(1))) void*)g,
        (__attribute__((address_space(3))) void*)l, 16, 0, 0);
}

// ---------- init: zero h buffers and carry (uint4-vectorized) ----------
__global__ void init_k(uint4* __restrict__ hh4, uint4* __restrict__ hl4, float4* __restrict__ cb4) {
    int i = blockIdx.x * 256 + threadIdx.x;           // grid covers 12*512*512/8
    uint4 z = make_uint4(0u, 0u, 0u, 0u);
    hh4[i] = z; hl4[i] = z;
    if (i < 256) cb4[i] = make_float4(0.f, 0.f, 0.f, 0.f);
}

// ---------- pack W' with K'-interleave (K'=2304, 6 segments) + bias4 ----------
// logit = sum over K' of A'(k')*B'(k'): segments give exactly
//   ah*bh + ah*bl + al*bh   (x part, k<256)  and same for h part (k>=256).
__global__ void pack_wq(const float* __restrict__ Wf, const float* __restrict__ bf_,
                        const float* __restrict__ Wi, const float* __restrict__ bi_,
                        const float* __restrict__ Wo, const float* __restrict__ bo_,
                        const float* __restrict__ Wg, const float* __restrict__ bg_,
                        u16* __restrict__ wq, float* __restrict__ bias4) {
    int idx = blockIdx.x * 256 + threadIdx.x;         // 2048*768 threads
    int n = idx / 768, k = idx - n * 768;
    int gate = n >> 9, col = n & 511;
    const float* W = (gate == 0) ? Wf : (gate == 1) ? Wi : (gate == 2) ? Wo : Wg;
    float v = W[k * 512 + col];
    u16 h = f2bf(v);
    u16 l = f2bf(v - bf2f(h));
    size_t base = (size_t)n * 2304;
    if (k < 256) {
        wq[base + k] = h; wq[base + 512 + k] = h; wq[base + 256 + k] = l;
    } else {
        int d = k - 256;
        wq[base + 768 + d] = h; wq[base + 1792 + d] = h; wq[base + 1280 + d] = l;
    }
    if (k == 0) {
        const float* bb = (gate == 0) ? bf_ : (gate == 1) ? bi_ : (gate == 2) ? bo_ : bg_;
        bias4[n] = bb[col];
    }
}

// ---------- split ALL x to hi/lo bf16 (hoisted out of the block loop) ----------
__global__ void split_x(const float* __restrict__ src, u16* __restrict__ oh, u16* __restrict__ ol) {
    int i = blockIdx.x * 256 + threadIdx.x;           // grid covers 256*512*256/4
    float4 v = ((const float4*)src)[i];
    u16 hx = f2bf(v.x), hy = f2bf(v.y), hz = f2bf(v.z), hw = f2bf(v.w);
    u16 lx = f2bf(v.x - bf2f(hx)), ly = f2bf(v.y - bf2f(hy));
    u16 lz = f2bf(v.z - bf2f(hz)), lw = f2bf(v.w - bf2f(hw));
    uint2 hv; hv.x = (u32)hx | ((u32)hy << 16); hv.y = (u32)hz | ((u32)hw << 16);
    uint2 lv; lv.x = (u32)lx | ((u32)ly << 16); lv.y = (u32)lz | ((u32)lw << 16);
    ((uint2*)oh)[i] = hv;
    ((uint2*)ol)[i] = lv;
}

// ============================================================================
// 8-phase GEMM — r8's FULLY-PINNED schedule verbatim (best measured: ~70 µs,
// MfmaUtil ~31%; r9's loosened variant regressed to 85 µs/25%), with runtime
// ktEnd so launch 0 skips the h-half of K' (h==0 -> exactly +0.0, bitwise-
// identical; measured working in r9).
// BM=BN=256, BK=64, 512 thr (2Mx4N waves), 16x16x32 MFMA, LDS 2x64KB dbuf.
// Per K-tile, 4 phases; two counted-vmcnt publish points (never drains
// mid-loop). FIFO invariant at tile entry: A1(kt) outstanding.
// ============================================================================
__global__ __launch_bounds__(512, 2) void gemm_q(
    const u16* __restrict__ xh, const u16* __restrict__ xl,
    const u16* __restrict__ hh, const u16* __restrict__ hl,
    const u16* __restrict__ wq, const float* __restrict__ bias4,
    float* __restrict__ lg, int gx, int ktEnd) {
    __shared__ __align__(16) u16 smem[65536];   // 2 bufs x 32768 u16 (128 KiB)

    const int tid = threadIdx.x;
    const int wid = tid >> 6, lane = tid & 63;
    const int l15 = lane & 15, l4 = lane >> 4;
    const int wm = wid >> 2, wn = wid & 3;

    // XCD rect: xcd owns (gx/8) bm x 8 bn (gx=24 -> 3x8; gx=8 -> 1x8)
    const int xcd = blockIdx.x & 7, rr_ = blockIdx.x >> 3;
    const int bmp = gx >> 3;
    const int bm = xcd * bmp + (rr_ % bmp);
    const int bn = rr_ / bmp;

    // ---- staging precomputes: per thread, 2 loads per 16KB unit ----
    // idx = q*512+tid; ro = idx>>3 (0..127), s = idx&7, chunk c = s^(ro&7)
    u32 aox[2][2], aoh[2][2], adst[2][2];   // [unit][q], elem offsets
    u32 boff[2][2], bdst[2][2];
#pragma unroll
    for (int q = 0; q < 2; ++q) {
        u32 idx = (u32)q * 512 + (u32)tid;
        u32 ro = idx >> 3, s = idx & 7, c = s ^ (ro & 7);
#pragma unroll
        for (int u = 0; u < 2; ++u) {
            u32 arow = (u32)bm * 256 + (ro & 63) + (ro >> 6) * 128 + (u32)u * 64;
            u32 alds = ((ro & 63) + (ro >> 6) * 128 + (u32)u * 64) * 64 + s * 8;
            aox[u][q] = arow * 256 + c * 8;
            aoh[u][q] = arow * 512 + c * 8;
            adst[u][q] = alds;
            u32 bcol = (u32)bn * 256 + (u32)u * 128 + ro;
            boff[u][q] = bcol * 2304 + c * 8;
            bdst[u][q] = 16384 + ((u32)u * 128 + ro) * 64 + s * 8;
        }
    }

    // ---- fragment read offsets (u16 units); swizzle folded ----
    u32 rA[8], rB[4], sK[2];
#pragma unroll
    for (int f = 0; f < 8; ++f) rA[f] = (u32)(wm * 128 + f * 16 + l15) * 64;
#pragma unroll
    for (int f = 0; f < 4; ++f) rB[f] = 16384u + (u32)(wn * 64 + f * 16 + l15) * 64;
#pragma unroll
    for (int ks = 0; ks < 2; ++ks) sK[ks] = (u32)(((ks * 4 + l4) ^ (lane & 7)) * 8);

    f32x4 acc[8][4];
#pragma unroll
    for (int f = 0; f < 8; ++f)
#pragma unroll
        for (int j = 0; j < 4; ++j) { acc[f][j].x = 0.f; acc[f][j].y = 0.f; acc[f][j].z = 0.f; acc[f][j].w = 0.f; }

    bf16x8 aH[4], bF[4];

#define STAGE_B(u) do {                                                       \
        gl2lds16(bsr + boff[u][0], smem + nb32 + bdst[u][0]);                 \
        gl2lds16(bsr + boff[u][1], smem + nb32 + bdst[u][1]); } while (0)
#define STAGE_A(u) do {                                                       \
        gl2lds16(as_ + (xp ? aox[u][0] : aoh[u][0]) + ako, smem + nb32 + adst[u][0]); \
        gl2lds16(as_ + (xp ? aox[u][1] : aoh[u][1]) + ako, smem + nb32 + adst[u][1]); } while (0)
#define RD_A(h, ks) do {                                                      \
        aH[0] = *(const bf16x8*)(smem + cb32 + rA[(h)*4+0] + sK[ks]);         \
        aH[1] = *(const bf16x8*)(smem + cb32 + rA[(h)*4+1] + sK[ks]);         \
        aH[2] = *(const bf16x8*)(smem + cb32 + rA[(h)*4+2] + sK[ks]);         \
        aH[3] = *(const bf16x8*)(smem + cb32 + rA[(h)*4+3] + sK[ks]); } while (0)
#define RD_B(ks) do {                                                         \
        bF[0] = *(const bf16x8*)(smem + cb32 + rB[0] + sK[ks]);               \
        bF[1] = *(const bf16x8*)(smem + cb32 + rB[1] + sK[ks]);               \
        bF[2] = *(const bf16x8*)(smem + cb32 + rB[2] + sK[ks]);               \
        bF[3] = *(const bf16x8*)(smem + cb32 + rB[3] + sK[ks]); } while (0)
#define MM16(hb) do {                                                         \
        __builtin_amdgcn_s_setprio(1);                                        \
        _Pragma("unroll")                                                     \
        for (int fi_ = 0; fi_ < 4; ++fi_)                                     \
            _Pragma("unroll")                                                 \
            for (int fj_ = 0; fj_ < 4; ++fj_)                                 \
                acc[(hb)*4+fi_][fj_] = __builtin_amdgcn_mfma_f32_16x16x32_bf16(\
                    aH[fi_], bF[fj_], acc[(hb)*4+fi_][fj_], 0, 0, 0);         \
        __builtin_amdgcn_s_setprio(0);                                        \
    } while (0)
#define BAR() do { __builtin_amdgcn_s_barrier(); __builtin_amdgcn_sched_barrier(0); } while (0)

    // ---- prologue: stage tile 0 (order B0,B1,A0,A1 = steady retire order) ----
    {
        const int nb32 = 0;
        const u16* bsr = wq;                      // kn = 0
        const u16* as_ = xh; const u32 ako = 0; const bool xp = true;
        STAGE_B(0); STAGE_B(1); STAGE_A(0); STAGE_A(1);
    }
    asm volatile("s_waitcnt vmcnt(2)" ::: "memory");  // A1(0) stays in flight
    BAR();

#pragma unroll 2
    for (int kt = 0; kt < ktEnd; ++kt) {
        const int cb32 = (kt & 1) << 15;
        const int nb32 = cb32 ^ 32768;
        const int kn = kt + 1;
        const bool stg = (kn < ktEnd);
        const u16* as_ = xh; u32 ako = 0; bool xp = true;
        if (stg) {
            if (kn < 12) { as_ = (kn >= 8) ? xl : xh; ako = (u32)(kn & 3) * 64; xp = true; }
            else { int s2 = kn - 12; as_ = (s2 >= 16) ? hl : hh; ako = (u32)(s2 & 7) * 64; xp = false; }
        }
        const u16* bsr = wq + (size_t)kn * 64;

        // ---- p0: (h0, ks0) ----
        if (stg) STAGE_B(0);
        RD_B(0); RD_A(0, 0);
        BAR();
        MM16(0);
        if (stg) asm volatile("s_waitcnt vmcnt(2)" ::: "memory");  // publish A1(kt)
        else     asm volatile("s_waitcnt vmcnt(0)" ::: "memory");  // final drain
        BAR();
        // ---- p1: (h1, ks0) ----
        if (stg) STAGE_B(1);
        RD_A(1, 0);
        BAR();
        MM16(1);
        BAR();
        // ---- p2: (h0, ks1) ----
        if (stg) STAGE_A(0);
        RD_B(1); RD_A(0, 1);
        BAR();
        MM16(0);
        BAR();
        // ---- p3: (h1, ks1) ----
        if (stg) STAGE_A(1);
        RD_A(1, 1);
        BAR();
        MM16(1);
        if (stg) asm volatile("s_waitcnt vmcnt(2)" ::: "memory");  // publish B0,B1,A0(kt+1)
        BAR();
    }
#undef STAGE_B
#undef STAGE_A
#undef RD_A
#undef RD_B
#undef MM16
#undef BAR

    // C/D layout (16x16): col = lane&15, row = (lane>>4)*4 + reg
#pragma unroll
    for (int fj = 0; fj < 4; ++fj) {
        int n = bn * 256 + wn * 64 + fj * 16 + l15;
        float bv = bias4[n];
#pragma unroll
        for (int f = 0; f < 8; ++f) {
            int row = bm * 256 + wm * 128 + f * 16 + l4 * 4;
            lg[(size_t)(row + 0) * 2048 + n] = acc[f][fj].x + bv;
            lg[(size_t)(row + 1) * 2048 + n] = acc[f][fj].y + bv;
            lg[(size_t)(row + 2) * 2048 + n] = acc[f][fj].z + bv;
            lg[(size_t)(row + 3) * 2048 + n] = acc[f][fj].w + bv;
        }
    }
}

// ---------- one sequential chain step: r <- tanh(softmax_f[rowb]*r + softmax_i[rowb]*tanh(g[rowb])) ----------
__device__ __forceinline__ void chain_step(const float* __restrict__ lg, int j, int lane, float r[8]) {
    int rowb = (j + 1) % 12;   // batch row (t+1)%P of c_t (t0 always multiple of 12)
    const float* base = lg + (size_t)(j * 512 + rowb) * 2048 + lane * 8;
    float f[8], iv[8], g[8];
#pragma unroll
    for (int u = 0; u < 8; ++u) { f[u] = base[u]; iv[u] = base[512 + u]; g[u] = base[1536 + u]; }
    float mf = -1e30f, mi = -1e30f;
#pragma unroll
    for (int u = 0; u < 8; ++u) { mf = fmaxf(mf, f[u]); mi = fmaxf(mi, iv[u]); }
#pragma unroll
    for (int o = 32; o; o >>= 1) { mf = fmaxf(mf, __shfl_xor(mf, o)); mi = fmaxf(mi, __shfl_xor(mi, o)); }
    float sf = 0.f, si = 0.f;
#pragma unroll
    for (int u = 0; u < 8; ++u) {
        f[u] = __expf(f[u] - mf); sf += f[u];
        iv[u] = __expf(iv[u] - mi); si += iv[u];
    }
#pragma unroll
    for (int o = 32; o; o >>= 1) { sf += __shfl_xor(sf, o); si += __shfl_xor(si, o); }
    float rf = __builtin_amdgcn_rcpf(sf), ri = __builtin_amdgcn_rcpf(si);
#pragma unroll
    for (int u = 0; u < 8; ++u) {
        float gg = ftanh(g[u]);
        r[u] = ftanh(f[u] * rf * r[u] + iv[u] * ri * gg);
    }
}

// ---------- gates (chain fused): wave 0 walks chain to its block's s; then all waves do
//            softmax f,i,o + tanh g, c_new, h row (hi/lo bf16), final out ----------
__global__ __launch_bounds__(256) void gates_k(
    const float* __restrict__ lg, float* __restrict__ cb,
    u16* __restrict__ hh, u16* __restrict__ hl,
    float* __restrict__ out, int t0, int S, int rd, int wr, int wrH) {
    __shared__ float rsh[512];
    const int widx = threadIdx.x >> 6, lane = threadIdx.x & 63;
    const int s = (S - 1) - (blockIdx.x >> 7);          // 128 blocks per s, longest chain first
    const int b = (blockIdx.x & 127) * 4 + widx;
    const int t = t0 + s;

    if (widx == 0) {
        float r[8];
#pragma unroll
        for (int u = 0; u < 8; ++u) r[u] = cb[rd * 512 + lane * 8 + u];
        for (int j = 0; j < s; ++j) chain_step(lg, j, lane, r);   // identical op sequence in every block -> bitwise-identical r
#pragma unroll
        for (int u = 0; u < 8; ++u) rsh[lane * 8 + u] = r[u];
        // carrier block (s == S-1, early dispatch) extends the chain one step, writes next-launch carry
        if ((int)blockIdx.x == 127 && t0 + S < 256) {
            chain_step(lg, S - 1, lane, r);
#pragma unroll
            for (int u = 0; u < 8; ++u) cb[wr * 512 + lane * 8 + u] = r[u];
        }
    }
    __syncthreads();

    const float* row = lg + (size_t)(s * 512 + b) * 2048 + lane * 8;
    float f[8], iv[8], ov[8], g[8];
#pragma unroll
    for (int u = 0; u < 8; ++u) {
        f[u] = row[u]; iv[u] = row[512 + u]; ov[u] = row[1024 + u]; g[u] = row[1536 + u];
    }
    float mf = -1e30f, mi = -1e30f, mo = -1e30f;
#pragma unroll
    for (int u = 0; u < 8; ++u) { mf = fmaxf(mf, f[u]); mi = fmaxf(mi, iv[u]); mo = fmaxf(mo, ov[u]); }
#pragma unroll
    for (int o = 32; o; o >>= 1) {
        mf = fmaxf(mf, __shfl_xor(mf, o));
        mi = fmaxf(mi, __shfl_xor(mi, o));
        mo = fmaxf(mo, __shfl_xor(mo, o));
    }
    float sf = 0.f, si = 0.f, so = 0.f;
#pragma unroll
    for (int u = 0; u < 8; ++u) {
        f[u] = __expf(f[u] - mf); sf += f[u];
        iv[u] = __expf(iv[u] - mi); si += iv[u];
        ov[u] = __expf(ov[u] - mo); so += ov[u];
    }
#pragma unroll
    for (int o = 32; o; o >>= 1) {
        sf += __shfl_xor(sf, o); si += __shfl_xor(si, o); so += __shfl_xor(so, o);
    }
    float rf = __builtin_amdgcn_rcpf(sf), ri = __builtin_amdgcn_rcpf(si), ro = __builtin_amdgcn_rcpf(so);
    float hout[8];
#pragma unroll
    for (int u = 0; u < 8; ++u) {
        float rr = rsh[lane * 8 + u];
        float gg = ftanh(g[u]);
        float cv = ftanh(f[u] * rf * rr + iv[u] * ri * gg);
        hout[u] = ov[u] * ro * cv;
    }
    if (wrH) {
        u32 hhp[4], hlp[4];
#pragma unroll
        for (int u = 0; u < 4; ++u) {
            u16 h0 = f2bf(hout[2 * u]), h1 = f2bf(hout[2 * u + 1]);
            u16 l0 = f2bf(hout[2 * u] - bf2f(h0)), l1 = f2bf(hout[2 * u + 1] - bf2f(h1));
            hhp[u] = (u32)h0 | ((u32)h1 << 16);
            hlp[u] = (u32)l0 | ((u32)l1 << 16);
        }
        size_t hb = ((size_t)(s * 512 + b)) * 512 + lane * 8;   // h row index = t%12 = s
        *(uint4*)&hh[hb] = make_uint4(hhp[0], hhp[1], hhp[2], hhp[3]);
        *(uint4*)&hl[hb] = make_uint4(hlp[0], hlp[1], hlp[2], hlp[3]);
    }
    if (t == 255) {
        float* op = out + (size_t)b * 512 + lane * 8;
#pragma unroll
        for (int u = 0; u < 8; ++u) op[u] = hout[u];
    }
}

extern "C" void kernel_launch(void* const* d_in, const int* in_sizes, int n_in,
                              void* d_out, int out_size, void* d_ws, size_t ws_size,
                              hipStream_t stream) {
    const float* x   = (const float*)d_in[0];
    const float* Wf  = (const float*)d_in[1];
    const float* bf_ = (const float*)d_in[2];
    const float* Wi  = (const float*)d_in[3];
    const float* bi_ = (const float*)d_in[4];
    const float* Wo  = (const float*)d_in[5];
    const float* bo_ = (const float*)d_in[6];
    const float* Wg  = (const float*)d_in[7];
    const float* bg_ = (const float*)d_in[8];
    float* out = (float*)d_out;

    char* p = (char*)d_ws;
    u16* xh  = (u16*)p; p += 134217728;     // [256*512, 256] bf16 hi (full sequence)
    u16* xl  = (u16*)p; p += 134217728;
    u16* wq  = (u16*)p; p += 9437184;       // [2048, 2304] K'-interleaved W'
    u16* hh  = (u16*)p; p += 6291456;       // [12, 512, 512] bf16 hi
    u16* hl  = (u16*)p; p += 6291456;
    float* bias4 = (float*)p; p += 8192;    // [2048]
    float* cb    = (float*)p; p += 4096;    // [2][512] carry double-buffer
    float* lg    = (float*)p; p += 50331648;// [12*512, 2048] fp32 logits
    // total ~341 MiB (ws poison shows 512 MiB available)

    init_k<<<3072, 256, 0, stream>>>((uint4*)hh, (uint4*)hl, (float4*)cb);
    pack_wq<<<6144, 256, 0, stream>>>(Wf, bf_, Wi, bi_, Wo, bo_, Wg, bg_, wq, bias4);
    split_x<<<32768, 256, 0, stream>>>(x, xh, xl);

    for (int blk = 0; blk < 22; ++blk) {
        int t0 = blk * 12;
        int S = (256 - t0 >= 12) ? 12 : (256 - t0);  // last block: 4 steps
        int M = S * 512;                             // 6144 or 2048: both % 256 == 0
        int gx = M / 256;                            // 24 or 8
        int ktEnd = (blk == 0) ? 12 : 36;            // blk 0: h==0 -> skip h-tiles (exact)
        int wrH = (t0 + S < 256) ? 1 : 0;            // last block's h rows never read
        gemm_q<<<gx * 8, 512, 0, stream>>>(
            xh + (size_t)t0 * 512 * 256, xl + (size_t)t0 * 512 * 256,
            hh, hl, wq, bias4, lg, gx, ktEnd);
        gates_k<<<S * 128, 256, 0, stream>>>(lg, cb, hh, hl, out, t0, S, blk & 1, (blk + 1) & 1, wrH);
    }
}

// Round 11
// 2086.436 us; speedup vs baseline: 1.0241x; 1.0241x over previous
//
#include <hip/hip_runtime.h>

typedef unsigned short u16;
typedef unsigned int   u32;

typedef __attribute__((ext_vector_type(8))) short bf16x8;
typedef __attribute__((ext_vector_type(16))) float f32x16;

// ---------- helpers ----------
__device__ __forceinline__ u16 f2bf(float v) {           // RNE fp32 -> bf16
    u32 u = __float_as_uint(v);
    u32 r = (u + 0x7fffu + ((u >> 16) & 1u)) >> 16;
    return (u16)r;
}
__device__ __forceinline__ float bf2f(u16 h) { return __uint_as_float(((u32)h) << 16); }

__device__ __forceinline__ float ftanh(float x) {        // tanh via exp, ~5 inst
    float e = __expf(2.0f * x);                          // inf for large x -> rcp gives 0 -> +1
    return 1.0f - 2.0f * __builtin_amdgcn_rcpf(e + 1.0f);
}

__device__ __forceinline__ void gl2lds16(const void* g, void* l) {
    __builtin_amdgcn_global_load_lds(
        (const __attribute__((address_space(1))) void*)g,
        (__attribute__((address_space(3))) void*)l, 16, 0, 0);
}

// ---------- init: zero h buffers and carry (uint4-vectorized) ----------
__global__ void init_k(uint4* __restrict__ hh4, uint4* __restrict__ hl4, float4* __restrict__ cb4) {
    int i = blockIdx.x * 256 + threadIdx.x;           // grid covers 12*512*512/8
    uint4 z = make_uint4(0u, 0u, 0u, 0u);
    hh4[i] = z; hl4[i] = z;
    if (i < 256) cb4[i] = make_float4(0.f, 0.f, 0.f, 0.f);
}

// ---------- pack W: W4t[n][k] = W_gate[k][col], hi/lo bf16 split; bias4[n] ----------
__global__ void pack_w(const float* __restrict__ Wf, const float* __restrict__ bf_,
                       const float* __restrict__ Wi, const float* __restrict__ bi_,
                       const float* __restrict__ Wo, const float* __restrict__ bo_,
                       const float* __restrict__ Wg, const float* __restrict__ bg_,
                       u16* __restrict__ wth, u16* __restrict__ wtl, float* __restrict__ bias4) {
    int idx = blockIdx.x * 256 + threadIdx.x;         // 2048*768 threads, wave-uniform n (768=12*64)
    int n = idx / 768, k = idx - n * 768;
    int gate = n >> 9, col = n & 511;
    const float* W = (gate == 0) ? Wf : (gate == 1) ? Wi : (gate == 2) ? Wo : Wg;
    float v = W[k * 512 + col];
    u16 h = f2bf(v);
    wth[idx] = h;
    wtl[idx] = f2bf(v - bf2f(h));
    if (k == 0) {
        const float* bb = (gate == 0) ? bf_ : (gate == 1) ? bi_ : (gate == 2) ? bo_ : bg_;
        bias4[n] = bb[col];
    }
}

// ---------- split ALL x to hi/lo bf16 (hoisted out of the block loop) ----------
__global__ void split_x(const float* __restrict__ src, u16* __restrict__ oh, u16* __restrict__ ol) {
    int i = blockIdx.x * 256 + threadIdx.x;           // grid covers 256*512*256/4
    float4 v = ((const float4*)src)[i];
    u16 hx = f2bf(v.x), hy = f2bf(v.y), hz = f2bf(v.z), hw = f2bf(v.w);
    u16 lx = f2bf(v.x - bf2f(hx)), ly = f2bf(v.y - bf2f(hy));
    u16 lz = f2bf(v.z - bf2f(hz)), lw = f2bf(v.w - bf2f(hw));
    uint2 hv; hv.x = (u32)hx | ((u32)hy << 16); hv.y = (u32)hz | ((u32)hw << 16);
    uint2 lv; lv.x = (u32)lx | ((u32)ly << 16); lv.y = (u32)lz | ((u32)lw << 16);
    ((uint2*)oh)[i] = hv;
    ((uint2*)ol)[i] = lv;
}

// ---------- bf16x3 GEMM: logits[m][n] = A[m][:]@W4[:, n] + bias4[n] ----------
// A[m][k<256]=x[t][b][k], A[m][256+k]=h_buf[s][b][k]; m=(s,b); 128x128 tile, BK=32
// 32x32x16 MFMA: 24 mfma + 16 ds_read_b128 per wave per K-iter.
// grid x = bm (48 = 0 mod 8) so all 16 bn-readers of one A-slice share an XCD L2.
// KEND template: 256 for chain-block 0 (h==0 -> h-segment contributes exactly
// +0.0; skipping is bitwise-identical), 768 otherwise. Compile-time bound so
// the staging branch folds (r10 lesson: runtime bound cost ~8 us/launch).
#define BK 32
template<int KEND>
__global__ __launch_bounds__(256, 3) void gemm_x3(
    const u16* __restrict__ xh, const u16* __restrict__ xl,
    const u16* __restrict__ hh, const u16* __restrict__ hl,
    const u16* __restrict__ wth, const u16* __restrict__ wtl,
    const float* __restrict__ bias4, float* __restrict__ lg) {
    __shared__ __align__(16) u16 Ah[128 * BK];
    __shared__ __align__(16) u16 Al[128 * BK];
    __shared__ __align__(16) u16 Bh[128 * BK];
    __shared__ __align__(16) u16 Bl[128 * BK];

    const int tid = threadIdx.x;
    const int wid = tid >> 6, lane = tid & 63;
    const int bm = blockIdx.x, bn = blockIdx.y;       // x = bm for XCD A-locality
    const int s = bm >> 2;                 // t%12 == s (t0 always multiple of 12)
    const int b0 = (bm & 3) * 128;
    const int laneR = lane >> 2;           // row within 16-row staging group
    const int laneC = (lane & 3) * 8;      // k element offset

    u16* lds = (wid == 0) ? Ah : (wid == 1) ? Al : (wid == 2) ? Bh : Bl;
    const u16* xp = (wid == 0) ? xh : xl;
    const u16* hp = (wid == 0) ? hh : hl;
    const u16* wp = (wid == 2) ? wth : wtl;
    const u16* xrow = xp + (size_t)(s * 512 + b0) * 256 + laneR * 256 + laneC;
    const u16* hrow = hp + (size_t)(s * 512 + b0) * 512 + laneR * 512 + laneC;
    const u16* wrow = wp + (size_t)(bn * 128) * 768 + laneR * 768 + laneC;

    const int wm = wid >> 1, wn = wid & 1;
    const int l32 = lane & 31, khalf = lane >> 5;     // A/B frag: row = lane&31, k = khalf*8+j

    f32x16 acc[2][2];
#pragma unroll
    for (int i = 0; i < 2; i++)
#pragma unroll
        for (int j = 0; j < 2; j++)
#pragma unroll
            for (int r = 0; r < 16; ++r) acc[i][j][r] = 0.f;

    for (int k0 = 0; k0 < KEND; k0 += BK) {
        __syncthreads();
        if (wid < 2) {
            if (k0 < 256) {
                const u16* src = xrow + k0;
#pragma unroll
                for (int r = 0; r < 8; ++r) gl2lds16(src + r * 16 * 256, lds + r * 16 * BK);
            } else {
                const u16* src = hrow + (k0 - 256);
#pragma unroll
                for (int r = 0; r < 8; ++r) gl2lds16(src + r * 16 * 512, lds + r * 16 * BK);
            }
        } else {
            const u16* src = wrow + k0;
#pragma unroll
            for (int r = 0; r < 8; ++r) gl2lds16(src + r * 16 * 768, lds + r * 16 * BK);
        }
        __syncthreads();

        bf16x8 a_h[2][2], a_l[2][2], b_h[2][2], b_l[2][2];   // [tile][k-step]
#pragma unroll
        for (int t = 0; t < 2; ++t)
#pragma unroll
            for (int ks = 0; ks < 2; ++ks) {
                int ko = ks * 16 + khalf * 8;
                a_h[t][ks] = *(const bf16x8*)&Ah[(wm * 64 + t * 32 + l32) * BK + ko];
                a_l[t][ks] = *(const bf16x8*)&Al[(wm * 64 + t * 32 + l32) * BK + ko];
                b_h[t][ks] = *(const bf16x8*)&Bh[(wn * 64 + t * 32 + l32) * BK + ko];
                b_l[t][ks] = *(const bf16x8*)&Bl[(wn * 64 + t * 32 + l32) * BK + ko];
            }
#pragma unroll
        for (int ks = 0; ks < 2; ++ks)
#pragma unroll
            for (int i = 0; i < 2; ++i)
#pragma unroll
                for (int j = 0; j < 2; ++j) {
                    acc[i][j] = __builtin_amdgcn_mfma_f32_32x32x16_bf16(a_h[i][ks], b_h[j][ks], acc[i][j], 0, 0, 0);
                    acc[i][j] = __builtin_amdgcn_mfma_f32_32x32x16_bf16(a_h[i][ks], b_l[j][ks], acc[i][j], 0, 0, 0);
                    acc[i][j] = __builtin_amdgcn_mfma_f32_32x32x16_bf16(a_l[i][ks], b_h[j][ks], acc[i][j], 0, 0, 0);
                }
    }

    // C/D layout (measured): col = lane&31, row = (reg&3) + 8*(reg>>2) + 4*(lane>>5)
#pragma unroll
    for (int j = 0; j < 2; ++j) {
        int n = bn * 128 + wn * 64 + j * 32 + l32;
        float bv = bias4[n];
#pragma unroll
        for (int i = 0; i < 2; ++i) {
            int rbase = wm * 64 + i * 32 + 4 * khalf;
#pragma unroll
            for (int r = 0; r < 16; ++r) {
                int row = rbase + (r & 3) + 8 * (r >> 2);
                __builtin_nontemporal_store(acc[i][j][r] + bv,
                    &lg[(size_t)(bm * 128 + row) * 2048 + n]);
            }
        }
    }
}

// ---------- one sequential chain step: r <- tanh(softmax_f[rowb]*r + softmax_i[rowb]*tanh(g[rowb])) ----------
__device__ __forceinline__ void chain_step(const float* __restrict__ lg, int j, int lane, float r[8]) {
    int rowb = (j + 1) % 12;   // batch row (t+1)%P of c_t (t0 always multiple of 12)
    const float* base = lg + (size_t)(j * 512 + rowb) * 2048 + lane * 8;
    float f[8], iv[8], g[8];
#pragma unroll
    for (int u = 0; u < 8; ++u) { f[u] = base[u]; iv[u] = base[512 + u]; g[u] = base[1536 + u]; }
    float mf = -1e30f, mi = -1e30f;
#pragma unroll
    for (int u = 0; u < 8; ++u) { mf = fmaxf(mf, f[u]); mi = fmaxf(mi, iv[u]); }
#pragma unroll
    for (int o = 32; o; o >>= 1) { mf = fmaxf(mf, __shfl_xor(mf, o)); mi = fmaxf(mi, __shfl_xor(mi, o)); }
    float sf = 0.f, si = 0.f;
#pragma unroll
    for (int u = 0; u < 8; ++u) {
        f[u] = __expf(f[u] - mf); sf += f[u];
        iv[u] = __expf(iv[u] - mi); si += iv[u];
    }
#pragma unroll
    for (int o = 32; o; o >>= 1) { sf += __shfl_xor(sf, o); si += __shfl_xor(si, o); }
    float rf = __builtin_amdgcn_rcpf(sf), ri = __builtin_amdgcn_rcpf(si);
#pragma unroll
    for (int u = 0; u < 8; ++u) {
        float gg = ftanh(g[u]);
        r[u] = ftanh(f[u] * rf * r[u] + iv[u] * ri * gg);
    }
}

// ---------- gates (chain fused): wave 0 walks chain to its block's s; then all waves do
//            softmax f,i,o + tanh g, c_new, h row (hi/lo bf16), final out ----------
// s reversed vs blockIdx so the longest redundant chains dispatch FIRST and overlap the bulk.
__global__ __launch_bounds__(256) void gates_k(
    const float* __restrict__ lg, float* __restrict__ cb,
    u16* __restrict__ hh, u16* __restrict__ hl,
    float* __restrict__ out, int t0, int S, int rd, int wr, int wrH) {
    __shared__ float rsh[512];
    const int widx = threadIdx.x >> 6, lane = threadIdx.x & 63;
    const int s = (S - 1) - (blockIdx.x >> 7);          // 128 blocks per s, longest chain first
    const int b = (blockIdx.x & 127) * 4 + widx;
    const int t = t0 + s;

    if (widx == 0) {
        float r[8];
#pragma unroll
        for (int u = 0; u < 8; ++u) r[u] = cb[rd * 512 + lane * 8 + u];
        for (int j = 0; j < s; ++j) chain_step(lg, j, lane, r);   // identical op sequence in every block -> bitwise-identical r
#pragma unroll
        for (int u = 0; u < 8; ++u) rsh[lane * 8 + u] = r[u];
        // carrier block (s == S-1, early dispatch) extends the chain one step, writes next-launch carry
        if ((int)blockIdx.x == 127 && t0 + S < 256) {
            chain_step(lg, S - 1, lane, r);
#pragma unroll
            for (int u = 0; u < 8; ++u) cb[wr * 512 + lane * 8 + u] = r[u];
        }
    }
    __syncthreads();

    const float* row = lg + (size_t)(s * 512 + b) * 2048 + lane * 8;
    float f[8], iv[8], ov[8], g[8];
#pragma unroll
    for (int u = 0; u < 8; ++u) {
        f[u] = row[u]; iv[u] = row[512 + u]; ov[u] = row[1024 + u]; g[u] = row[1536 + u];
    }
    float mf = -1e30f, mi = -1e30f, mo = -1e30f;
#pragma unroll
    for (int u = 0; u < 8; ++u) { mf = fmaxf(mf, f[u]); mi = fmaxf(mi, iv[u]); mo = fmaxf(mo, ov[u]); }
#pragma unroll
    for (int o = 32; o; o >>= 1) {
        mf = fmaxf(mf, __shfl_xor(mf, o));
        mi = fmaxf(mi, __shfl_xor(mi, o));
        mo = fmaxf(mo, __shfl_xor(mo, o));
    }
    float sf = 0.f, si = 0.f, so = 0.f;
#pragma unroll
    for (int u = 0; u < 8; ++u) {
        f[u] = __expf(f[u] - mf); sf += f[u];
        iv[u] = __expf(iv[u] - mi); si += iv[u];
        ov[u] = __expf(ov[u] - mo); so += ov[u];
    }
#pragma unroll
    for (int o = 32; o; o >>= 1) {
        sf += __shfl_xor(sf, o); si += __shfl_xor(si, o); so += __shfl_xor(so, o);
    }
    float rf = __builtin_amdgcn_rcpf(sf), ri = __builtin_amdgcn_rcpf(si), ro = __builtin_amdgcn_rcpf(so);
    float hout[8];
#pragma unroll
    for (int u = 0; u < 8; ++u) {
        float rr = rsh[lane * 8 + u];
        float gg = ftanh(g[u]);
        float cv = ftanh(f[u] * rf * rr + iv[u] * ri * gg);
        hout[u] = ov[u] * ro * cv;
    }
    if (wrH) {
        u32 hhp[4], hlp[4];
#pragma unroll
        for (int u = 0; u < 4; ++u) {
            u16 h0 = f2bf(hout[2 * u]), h1 = f2bf(hout[2 * u + 1]);
            u16 l0 = f2bf(hout[2 * u] - bf2f(h0)), l1 = f2bf(hout[2 * u + 1] - bf2f(h1));
            hhp[u] = (u32)h0 | ((u32)h1 << 16);
            hlp[u] = (u32)l0 | ((u32)l1 << 16);
        }
        size_t hb = ((size_t)(s * 512 + b)) * 512 + lane * 8;   // h row index = t%12 = s
        *(uint4*)&hh[hb] = make_uint4(hhp[0], hhp[1], hhp[2], hhp[3]);
        *(uint4*)&hl[hb] = make_uint4(hlp[0], hlp[1], hlp[2], hlp[3]);
    }
    if (t == 255) {
        float* op = out + (size_t)b * 512 + lane * 8;
#pragma unroll
        for (int u = 0; u < 8; ++u) op[u] = hout[u];
    }
}

extern "C" void kernel_launch(void* const* d_in, const int* in_sizes, int n_in,
                              void* d_out, int out_size, void* d_ws, size_t ws_size,
                              hipStream_t stream) {
    const float* x   = (const float*)d_in[0];
    const float* Wf  = (const float*)d_in[1];
    const float* bf_ = (const float*)d_in[2];
    const float* Wi  = (const float*)d_in[3];
    const float* bi_ = (const float*)d_in[4];
    const float* Wo  = (const float*)d_in[5];
    const float* bo_ = (const float*)d_in[6];
    const float* Wg  = (const float*)d_in[7];
    const float* bg_ = (const float*)d_in[8];
    float* out = (float*)d_out;

    char* p = (char*)d_ws;
    u16* xh  = (u16*)p; p += 134217728;     // [256*512, 256] bf16 hi (full sequence)
    u16* xl  = (u16*)p; p += 134217728;
    u16* wth = (u16*)p; p += 3145728;       // [2048, 768] bf16 hi (transposed W4)
    u16* wtl = (u16*)p; p += 3145728;
    u16* hh  = (u16*)p; p += 6291456;       // [12, 512, 512] bf16 hi
    u16* hl  = (u16*)p; p += 6291456;
    float* bias4 = (float*)p; p += 8192;    // [2048]
    float* cb    = (float*)p; p += 4096;    // [2][512] carry double-buffer
    float* lg    = (float*)p; p += 50331648;// [12*512, 2048] fp32 logits
    // total ~322 MiB (ws poison shows 512 MiB available)

    init_k<<<3072, 256, 0, stream>>>((uint4*)hh, (uint4*)hl, (float4*)cb);
    pack_w<<<6144, 256, 0, stream>>>(Wf, bf_, Wi, bi_, Wo, bo_, Wg, bg_, wth, wtl, bias4);
    split_x<<<32768, 256, 0, stream>>>(x, xh, xl);

    for (int blk = 0; blk < 22; ++blk) {
        int t0 = blk * 12;
        int S = (256 - t0 >= 12) ? 12 : (256 - t0);  // last block: 4 steps
        int wrH = (t0 + S < 256) ? 1 : 0;            // last block's h rows never read
        if (blk == 0) {
            gemm_x3<256><<<dim3(S * 4, 16), 256, 0, stream>>>(   // h==0: skip h-segment (exact)
                xh + (size_t)t0 * 512 * 256, xl + (size_t)t0 * 512 * 256,
                hh, hl, wth, wtl, bias4, lg);
        } else {
            gemm_x3<768><<<dim3(S * 4, 16), 256, 0, stream>>>(   // x = bm: A-slice readers share an XCD
                xh + (size_t)t0 * 512 * 256, xl + (size_t)t0 * 512 * 256,
                hh, hl, wth, wtl, bias4, lg);
        }
        gates_k<<<S * 128, 256, 0, stream>>>(lg, cb, hh, hl, out, t0, S, blk & 1, (blk + 1) & 1, wrH);
    }
}